// Round 2
// baseline (3308.937 us; speedup 1.0000x reference)
//
#include <hip/hip_runtime.h>
#include <math.h>

// ---------------------------------------------------------------------------
// MultiTemporalCrossTransformer — factorized algorithm.
// Frames: 12, tuples T=220=C(12,3), dim 1152, heads 2x576, way 5, shot 5,
// queries 50, supports 25.
//
// Key identities (biases folded as b/3 into each frame projection):
//   x_k[n,t] = sum_i Pk_i[n, f_i]           (pre-LN k features)
//   x_v[n,t] = sum_j Pv_j[n, f_j]           (v features, no LN)
//   LN(x) = r*(x-mu)*g + b_ln  with mu, var from per-frame means + self-Gram
//   score_h(q,k) = [r_q r_k (GG - mu_k ZGq - mu_q ZGk + mu_q mu_k Gg)
//                   + r_q (ZBq - mu_q Gb) + r_k (ZBk - mu_k Gb) + Bb] / 24
//   where GG = sum_{i,j} G_h[(qn,f_i,i),(sn,f_j,j)]  (g^2-weighted cross-Gram)
//   proto = M_h @ V_h with M = tuple-marginalized softmax weights.
// ---------------------------------------------------------------------------

#define NROWS 900     // 75 seqs * 12 frames
#define NPROJ 2700    // 75 * 36 frame-projections
#define DIM 1152
#define HDIM 576
#define NTUP 220
#define CHUNK 16      // query-tuples per attn block (LDS budget: keep < 64KB)

// ---------------- init: tuple tables, inverse lists, g/b constants ---------
__global__ __launch_bounds__(256) void init_tables(
    const float* __restrict__ g, const float* __restrict__ bb,
    int* __restrict__ tup, int* __restrict__ cnt, int* __restrict__ lists,
    float* __restrict__ consts)
{
  const int tid = threadIdx.x;
  if (tid < 220) {
    int t = tid, idx = 0;
    for (int a = 0; a < 10; a++)
      for (int b2 = a + 1; b2 < 11; b2++)
        for (int c = b2 + 1; c < 12; c++) {
          if (idx == t) { tup[t*3+0]=a; tup[t*3+1]=b2; tup[t*3+2]=c; }
          idx++;
        }
  }
  __syncthreads();
  if (tid < 36) {
    int j = tid / 12, p = tid % 12, c = 0;
    for (int t = 0; t < 220; t++)
      if (tup[t*3+j] == p) lists[tid*64 + (c++)] = t;
    cnt[tid] = c;
  }
  __shared__ float rd[6];
  if (tid < 6) rd[tid] = 0.f;
  __syncthreads();
  float s[6] = {0,0,0,0,0,0};
  for (int d = tid; d < DIM; d += 256) {
    float gv = g[d], bv = bb[d];
    int h = (d >= HDIM);
    s[h]     += gv*gv;
    s[2 + h] += gv*bv;
    s[4 + h] += bv*bv;
  }
  for (int i = 0; i < 6; i++) atomicAdd(&rd[i], s[i]);
  __syncthreads();
  if (tid < 6) consts[tid] = rd[tid];
}

// ---------------- positional encoding (float64, matches numpy) -------------
__global__ __launch_bounds__(256) void pe_kernel(float* __restrict__ PE)
{
  int idx = blockIdx.x * 256 + threadIdx.x;
  if (idx >= 12 * DIM) return;
  int p = idx / DIM, d = idx - p * DIM;
  int j = d >> 1;
  double div = exp((double)(2 * j) * (-9.210340371976184 / 1152.0)); // -ln(1e4)/1152
  double ang = (double)p * div;
  double v = (d & 1) ? cos(ang) : sin(ang);
  PE[idx] = (float)(v * 0.1);
}

// ---------------- F = input + PE -------------------------------------------
__global__ __launch_bounds__(256) void add_pe(
    const float* __restrict__ sup, const float* __restrict__ qry,
    const float* __restrict__ PE, float* __restrict__ F)
{
  int idx = blockIdx.x * 256 + threadIdx.x;
  if (idx >= NROWS * DIM) return;
  int row = idx / DIM, d = idx - row * DIM;
  int p = row % 12;
  float x = (row < 300) ? sup[idx] : qry[idx - 300 * DIM];
  F[idx] = x + PE[p * DIM + d];
}

// ---------------- projection GEMM: C[900,6912] = F @ [kW|vW] + b/3 ---------
// Output scattered into Ck[u][p][i][d], Cv[u][p][j][d]  (rows = NPROJ).
__global__ __launch_bounds__(256) void gemm_proj(
    const float* __restrict__ F, const float* __restrict__ kw,
    const float* __restrict__ vw, const float* __restrict__ kb,
    const float* __restrict__ vb, float* __restrict__ Ck, float* __restrict__ Cv)
{
  __shared__ float As[32][65];   // [k][m]
  __shared__ float Bs[32][65];   // [k][n]
  const int tid = threadIdx.x;
  const int col0 = blockIdx.x * 64;          // 0..6848
  const int row0 = blockIdx.y * 64;          // 0..896
  const int b = col0 / DIM;                  // 0..5
  const int d0 = col0 - b * DIM;
  const float* W = (b < 3) ? (kw + (size_t)(b * DIM) * DIM + d0)
                           : (vw + (size_t)((b - 3) * DIM) * DIM + d0);
  const int ty = tid / 16, tx = tid % 16;
  float acc[4][4];
  #pragma unroll
  for (int i = 0; i < 4; i++)
    #pragma unroll
    for (int j = 0; j < 4; j++) acc[i][j] = 0.f;

  for (int k0 = 0; k0 < DIM; k0 += 32) {
    { // load A tile 64x32
      int m = tid >> 2, kk = (tid & 3) * 8;
      int gm = row0 + m;
      if (gm < NROWS) {
        const float* src = F + (size_t)gm * DIM + k0 + kk;
        #pragma unroll
        for (int e = 0; e < 8; e++) As[kk + e][m] = src[e];
      } else {
        #pragma unroll
        for (int e = 0; e < 8; e++) As[kk + e][m] = 0.f;
      }
    }
    { // load B tile 32x64
      int kk = tid >> 3, n0 = (tid & 7) * 8;
      const float* src = W + (size_t)(k0 + kk) * DIM + n0;
      #pragma unroll
      for (int e = 0; e < 8; e++) Bs[kk][n0 + e] = src[e];
    }
    __syncthreads();
    #pragma unroll 8
    for (int kk = 0; kk < 32; kk++) {
      float a0 = As[kk][ty*4+0], a1 = As[kk][ty*4+1], a2 = As[kk][ty*4+2], a3 = As[kk][ty*4+3];
      float b0 = Bs[kk][tx*4+0], b1 = Bs[kk][tx*4+1], b2 = Bs[kk][tx*4+2], b3 = Bs[kk][tx*4+3];
      acc[0][0]+=a0*b0; acc[0][1]+=a0*b1; acc[0][2]+=a0*b2; acc[0][3]+=a0*b3;
      acc[1][0]+=a1*b0; acc[1][1]+=a1*b1; acc[1][2]+=a1*b2; acc[1][3]+=a1*b3;
      acc[2][0]+=a2*b0; acc[2][1]+=a2*b1; acc[2][2]+=a2*b2; acc[2][3]+=a2*b3;
      acc[3][0]+=a3*b0; acc[3][1]+=a3*b1; acc[3][2]+=a3*b2; acc[3][3]+=a3*b3;
    }
    __syncthreads();
  }
  #pragma unroll
  for (int i = 0; i < 4; i++) {
    int gm = row0 + ty * 4 + i;
    if (gm >= NROWS) continue;
    #pragma unroll
    for (int j = 0; j < 4; j++) {
      int d = d0 + tx * 4 + j;
      float val = acc[i][j];
      if (b < 3) Ck[((size_t)gm * 3 + b)       * DIM + d] = val + kb[d] * (1.f/3.f);
      else       Cv[((size_t)gm * 3 + (b - 3)) * DIM + d] = val + vb[d] * (1.f/3.f);
    }
  }
}

// ---------------- per frame-projection row stats ---------------------------
__global__ __launch_bounds__(128) void row_stats(
    const float* __restrict__ Ck, const float* __restrict__ g,
    const float* __restrict__ bb, float* __restrict__ m_o,
    float* __restrict__ A_o, float* __restrict__ B_o)
{
  const int r = blockIdx.x, tid = threadIdx.x;
  const float* x = Ck + (size_t)r * DIM;
  float sm = 0, sa0 = 0, sa1 = 0, sb0 = 0, sb1 = 0;
  for (int d = tid; d < DIM; d += 128) {
    float xv = x[d], gv = g[d], bv = bb[d];
    float xg2 = xv * gv * gv, xgb = xv * gv * bv;
    if (d < HDIM) { sa0 += xg2; sb0 += xgb; } else { sa1 += xg2; sb1 += xgb; }
    sm += xv;
  }
  for (int o = 32; o > 0; o >>= 1) {
    sm  += __shfl_down(sm, o);  sa0 += __shfl_down(sa0, o); sa1 += __shfl_down(sa1, o);
    sb0 += __shfl_down(sb0, o); sb1 += __shfl_down(sb1, o);
  }
  __shared__ float red[2][5];
  if ((tid & 63) == 0) {
    int wv = tid >> 6;
    red[wv][0]=sm; red[wv][1]=sa0; red[wv][2]=sa1; red[wv][3]=sb0; red[wv][4]=sb1;
  }
  __syncthreads();
  if (tid == 0) {
    m_o[r]            = (red[0][0] + red[1][0]) * (1.f / 1152.f);
    A_o[r]            =  red[0][1] + red[1][1];
    A_o[NPROJ + r]    =  red[0][2] + red[1][2];
    B_o[r]            =  red[0][3] + red[1][3];
    B_o[NPROJ + r]    =  red[0][4] + red[1][4];
  }
}

// ---------------- per-sequence 36x36 self-Gram (full 1152 dims) ------------
__global__ __launch_bounds__(256) void self_gram(
    const float* __restrict__ Ck, float* __restrict__ S)
{
  const int u = blockIdx.x, tid = threadIdx.x;
  __shared__ float CS[36][129];
  float acc[2][3] = {{0,0,0},{0,0,0}};
  const int ta = tid / 12, tb = tid - (tid / 12) * 12;
  for (int k0 = 0; k0 < DIM; k0 += 128) {
    __syncthreads();
    for (int idx = tid; idx < 36 * 128; idx += 256) {
      int rr = idx >> 7, kk = idx & 127;
      CS[rr][kk] = Ck[((size_t)u * 36 + rr) * DIM + k0 + kk];
    }
    __syncthreads();
    if (ta < 18) {
      for (int kk = 0; kk < 128; kk++) {
        float va0 = CS[ta*2][kk], va1 = CS[ta*2+1][kk];
        float vb0 = CS[tb*3][kk], vb1 = CS[tb*3+1][kk], vb2 = CS[tb*3+2][kk];
        acc[0][0]+=va0*vb0; acc[0][1]+=va0*vb1; acc[0][2]+=va0*vb2;
        acc[1][0]+=va1*vb0; acc[1][1]+=va1*vb1; acc[1][2]+=va1*vb2;
      }
    }
  }
  if (ta < 18) {
    #pragma unroll
    for (int i = 0; i < 2; i++)
      #pragma unroll
      for (int j = 0; j < 3; j++)
        S[u * 1296 + (ta*2+i) * 36 + tb*3+j] = acc[i][j];
  }
}

// ---------------- per-(seq, tuple) LN stats: mu, r, ZG_h, ZB_h -------------
__global__ __launch_bounds__(256) void row_ln(
    const float* __restrict__ S, const float* __restrict__ m_i,
    const float* __restrict__ A_i, const float* __restrict__ B_i,
    const int* __restrict__ tup, float* __restrict__ mu_o, float* __restrict__ r_o,
    float* __restrict__ zg_o, float* __restrict__ zb_o)
{
  const int u = blockIdx.x, tid = threadIdx.x;
  __shared__ float Ss[36][36];
  __shared__ float ms[36], As[2][36], Bs[2][36];
  for (int idx = tid; idx < 1296; idx += 256) (&Ss[0][0])[idx] = S[u * 1296 + idx];
  if (tid < 36) {
    ms[tid]    = m_i[u * 36 + tid];
    As[0][tid] = A_i[u * 36 + tid];  As[1][tid] = A_i[NPROJ + u * 36 + tid];
    Bs[0][tid] = B_i[u * 36 + tid];  Bs[1][tid] = B_i[NPROJ + u * 36 + tid];
  }
  __syncthreads();
  if (tid < NTUP) {
    int a0 = tup[tid*3+0]*3+0, a1 = tup[tid*3+1]*3+1, a2 = tup[tid*3+2]*3+2;
    float mu = ms[a0] + ms[a1] + ms[a2];
    float qq = Ss[a0][a0] + Ss[a1][a1] + Ss[a2][a2]
             + 2.f * (Ss[a0][a1] + Ss[a0][a2] + Ss[a1][a2]);
    float var = qq * (1.f / 1152.f) - mu * mu;
    float rr = rsqrtf(var + 1e-5f);
    mu_o[u * NTUP + tid] = mu;
    r_o [u * NTUP + tid] = rr;
    zg_o[u * NTUP + tid]           = As[0][a0] + As[0][a1] + As[0][a2];
    zg_o[16500 + u * NTUP + tid]   = As[1][a0] + As[1][a1] + As[1][a2];
    zb_o[u * NTUP + tid]           = Bs[0][a0] + Bs[0][a1] + Bs[0][a2];
    zb_o[16500 + u * NTUP + tid]   = Bs[1][a0] + Bs[1][a1] + Bs[1][a2];
  }
}

// ---------------- cross-Gram (g^2-weighted, per head): G[h][1800][900] -----
__global__ __launch_bounds__(256) void cross_gram(
    const float* __restrict__ Ck, const float* __restrict__ g, float* __restrict__ G)
{
  __shared__ float As[32][65], Bs[32][65];
  const int n0 = blockIdx.x * 64, m0 = blockIdx.y * 64, h = blockIdx.z;
  const int tid = threadIdx.x;
  const int ty = tid / 16, tx = tid % 16;
  const float* Ar = Ck + (size_t)900 * DIM + h * HDIM;  // query frame-proj rows
  const float* Br = Ck + h * HDIM;                       // support rows
  const float* gh = g + h * HDIM;
  float acc[4][4];
  #pragma unroll
  for (int i = 0; i < 4; i++)
    #pragma unroll
    for (int j = 0; j < 4; j++) acc[i][j] = 0.f;

  for (int k0 = 0; k0 < HDIM; k0 += 32) {
    int mm = tid >> 2, kk = (tid & 3) * 8;
    int gm = m0 + mm, gn = n0 + mm;
    if (gm < 1800) {
      const float* src = Ar + (size_t)gm * DIM + k0 + kk;
      #pragma unroll
      for (int e = 0; e < 8; e++) { float gv = gh[k0 + kk + e]; As[kk+e][mm] = src[e] * gv * gv; }
    } else {
      #pragma unroll
      for (int e = 0; e < 8; e++) As[kk+e][mm] = 0.f;
    }
    if (gn < 900) {
      const float* src = Br + (size_t)gn * DIM + k0 + kk;
      #pragma unroll
      for (int e = 0; e < 8; e++) Bs[kk+e][mm] = src[e];
    } else {
      #pragma unroll
      for (int e = 0; e < 8; e++) Bs[kk+e][mm] = 0.f;
    }
    __syncthreads();
    #pragma unroll 8
    for (int k2 = 0; k2 < 32; k2++) {
      float a0 = As[k2][ty*4+0], a1 = As[k2][ty*4+1], a2 = As[k2][ty*4+2], a3 = As[k2][ty*4+3];
      float b0 = Bs[k2][tx*4+0], b1 = Bs[k2][tx*4+1], b2 = Bs[k2][tx*4+2], b3 = Bs[k2][tx*4+3];
      acc[0][0]+=a0*b0; acc[0][1]+=a0*b1; acc[0][2]+=a0*b2; acc[0][3]+=a0*b3;
      acc[1][0]+=a1*b0; acc[1][1]+=a1*b1; acc[1][2]+=a1*b2; acc[1][3]+=a1*b3;
      acc[2][0]+=a2*b0; acc[2][1]+=a2*b1; acc[2][2]+=a2*b2; acc[2][3]+=a2*b3;
      acc[3][0]+=a3*b0; acc[3][1]+=a3*b1; acc[3][2]+=a3*b2; acc[3][3]+=a3*b3;
    }
    __syncthreads();
  }
  #pragma unroll
  for (int i = 0; i < 4; i++) {
    int gm = m0 + ty * 4 + i;
    if (gm >= 1800) continue;
    #pragma unroll
    for (int j = 0; j < 4; j++) {
      int gn = n0 + tx * 4 + j;
      if (gn < 900) G[((size_t)h * 1800 + gm) * 900 + gn] = acc[i][j];
    }
  }
}

// ---------------- fused scores + softmax + marginals + PV + distance -------
// Static LDS budget (< 64 KB): ScorePhase 48.4KB (union w/ PVPhase 41.8KB)
// + M[16][180] 11.5KB + tables ~3KB + red  => ~62.9KB total.
struct ScorePhase {
  float Gs[5][36][36];
  float muk[5][220], rk[5][220], zgk[5][220], zbk[5][220];
  float sc[1104];
  float muq[CHUNK], rq[CHUNK], zgq[CHUNK], zbq[CHUNK];
  int   aq[CHUNK][3];
};
struct PVPhase { float Vt[18][580]; };
union SmemU { ScorePhase s; PVPhase p; };

__global__ __launch_bounds__(256) void attn_kernel(
    const float* __restrict__ G, const float* __restrict__ Cv,
    const float* __restrict__ mu_g, const float* __restrict__ r_g,
    const float* __restrict__ zg_g, const float* __restrict__ zb_g,
    const int* __restrict__ tup_g, const int* __restrict__ cnt_g,
    const int* __restrict__ lists_g, const float* __restrict__ consts,
    float* __restrict__ out)
{
  __shared__ float M[CHUNK][180];
  __shared__ unsigned char tupS[220][3];
  __shared__ unsigned char listsS[36][64];
  __shared__ unsigned char cntS[36];
  __shared__ float red[8];
  __shared__ SmemU u;

  const int tid = threadIdx.x;
  const int chunk = blockIdx.x, w = blockIdx.y;
  const int qu = blockIdx.z >> 1, h = blockIdx.z & 1;
  const int tbase = chunk * CHUNK;
  const int nt = min(CHUNK, 220 - tbase);

  // ---- stage ----
  for (int idx = tid; idx < 6480; idx += 256) {
    int s = idx / 1296, rem = idx % 1296;
    u.s.Gs[s][rem / 36][rem % 36] =
        G[((size_t)h * 1800 + qu * 36 + rem / 36) * 900 + (w * 5 + s) * 36 + rem % 36];
  }
  for (int idx = tid; idx < 1100; idx += 256) {
    int s = idx / 220, t2 = idx - s * 220, uu = w * 5 + s;
    u.s.muk[s][t2] = mu_g[uu * 220 + t2];
    u.s.rk [s][t2] = r_g [uu * 220 + t2];
    u.s.zgk[s][t2] = zg_g[h * 16500 + uu * 220 + t2];
    u.s.zbk[s][t2] = zb_g[h * 16500 + uu * 220 + t2];
  }
  for (int idx = tid; idx < 660;  idx += 256) (&tupS[0][0])[idx]   = (unsigned char)tup_g[idx];
  for (int idx = tid; idx < 2304; idx += 256) (&listsS[0][0])[idx] = (unsigned char)lists_g[idx];
  if (tid < 36) cntS[tid] = (unsigned char)cnt_g[tid];
  if (tid < nt) {
    int t = tbase + tid;
    u.s.muq[tid] = mu_g[(25 + qu) * 220 + t];
    u.s.rq [tid] = r_g [(25 + qu) * 220 + t];
    u.s.zgq[tid] = zg_g[h * 16500 + (25 + qu) * 220 + t];
    u.s.zbq[tid] = zb_g[h * 16500 + (25 + qu) * 220 + t];
    u.s.aq[tid][0] = tup_g[t*3+0] * 3 + 0;
    u.s.aq[tid][1] = tup_g[t*3+1] * 3 + 1;
    u.s.aq[tid][2] = tup_g[t*3+2] * 3 + 2;
  }
  for (int idx = tid; idx < CHUNK * 180; idx += 256) (&M[0][0])[idx] = 0.f;
  __syncthreads();

  const float Ggh = consts[h], Gbh = consts[2 + h], Bbh = consts[4 + h];

  // ---- scores + softmax + marginals, one query-tuple at a time ----
  for (int tl = 0; tl < nt; ++tl) {
    const float mq = u.s.muq[tl], rqv = u.s.rq[tl], zgqv = u.s.zgq[tl], zbqv = u.s.zbq[tl];
    const int a0 = u.s.aq[tl][0], a1 = u.s.aq[tl][1], a2 = u.s.aq[tl][2];
    float lmax = -1e30f;
    for (int e = tid; e < 1100; e += 256) {
      int s = e / 220, t2 = e - s * 220;
      int b0 = tupS[t2][0]*3, b1 = tupS[t2][1]*3+1, b2 = tupS[t2][2]*3+2;
      const float* g0 = u.s.Gs[s][a0];
      const float* g1 = u.s.Gs[s][a1];
      const float* g2 = u.s.Gs[s][a2];
      float GG = g0[b0]+g0[b1]+g0[b2] + g1[b0]+g1[b1]+g1[b2] + g2[b0]+g2[b1]+g2[b2];
      float mk = u.s.muk[s][t2], rk = u.s.rk[s][t2];
      float zgkv = u.s.zgk[s][t2], zbkv = u.s.zbk[s][t2];
      float wqk = GG - mk * zgqv - mq * zgkv + mq * mk * Ggh;
      float scv = rqv * rk * wqk + rqv * (zbqv - mq * Gbh) + rk * (zbkv - mk * Gbh) + Bbh;
      scv *= (1.0f / 24.0f);
      u.s.sc[e] = scv;
      lmax = fmaxf(lmax, scv);
    }
    for (int o = 32; o > 0; o >>= 1) lmax = fmaxf(lmax, __shfl_down(lmax, o));
    if ((tid & 63) == 0) red[tid >> 6] = lmax;
    __syncthreads();
    if (tid == 0) red[4] = fmaxf(fmaxf(red[0], red[1]), fmaxf(red[2], red[3]));
    __syncthreads();
    const float mx = red[4];
    float lsum = 0.f;
    for (int e = tid; e < 1100; e += 256) {
      float v = __expf(u.s.sc[e] - mx);
      u.s.sc[e] = v;
      lsum += v;
    }
    for (int o = 32; o > 0; o >>= 1) lsum += __shfl_down(lsum, o);
    if ((tid & 63) == 0) red[tid >> 6] = lsum;
    __syncthreads();
    if (tid == 0) red[5] = red[0] + red[1] + red[2] + red[3];
    __syncthreads();
    const float inv = 1.0f / red[5];
    if (tid < 180) {
      int j = tid / 60, rem = tid - j * 60, s = rem / 12, p = rem - (rem / 12) * 12;
      int c = cntS[j * 12 + p];
      const unsigned char* L = listsS[j * 12 + p];
      const float* scp = &u.s.sc[s * 220];
      float a = 0.f;
      for (int ii = 0; ii < c; ++ii) a += scp[L[ii]];
      M[tl][tid] = a * inv;
    }
    __syncthreads();
  }

  // ---- PV: proto = M @ V_h, fused squared-distance vs q_vs ----
  float acc[2][18];
  #pragma unroll
  for (int i = 0; i < 2; i++)
    #pragma unroll
    for (int e = 0; e < 18; e++) acc[i][e] = 0.f;

  const int ty = tid >> 5, tx = tid & 31;    // ty 0..7, tx 0..31
  const int tq0 = ty * 2, dd0 = tx * 18;
  for (int c = 0; c < 10; c++) {
    __syncthreads();
    for (int idx = tid; idx < 18 * 576; idx += 256) {
      int kk = idx / 576, dd = idx - kk * 576;
      int kg = c * 18 + kk;
      int j = kg / 60, rem = kg - j * 60, s = rem / 12, p = rem - (rem / 12) * 12;
      u.p.Vt[kk][dd] = Cv[((size_t)((w * 5 + s) * 36 + p * 3 + j)) * DIM + h * HDIM + dd];
    }
    __syncthreads();
    for (int kk = 0; kk < 18; kk++) {
      int kg = c * 18 + kk;
      float mv0 = M[tq0+0][kg], mv1 = M[tq0+1][kg];
      #pragma unroll
      for (int e = 0; e < 18; e++) {
        float vv = u.p.Vt[kk][dd0 + e];
        acc[0][e] += mv0 * vv; acc[1][e] += mv1 * vv;
      }
    }
  }

  float sq = 0.f;
  for (int i = 0; i < 2; i++) {
    int t = tbase + tq0 + i;
    if (t < 220) {
      int f0 = tupS[t][0], f1 = tupS[t][1], f2 = tupS[t][2];
      const float* c0 = &Cv[((size_t)((25+qu)*36 + f0*3+0)) * DIM + h * HDIM + dd0];
      const float* c1 = &Cv[((size_t)((25+qu)*36 + f1*3+1)) * DIM + h * HDIM + dd0];
      const float* c2 = &Cv[((size_t)((25+qu)*36 + f2*3+2)) * DIM + h * HDIM + dd0];
      #pragma unroll
      for (int e = 0; e < 18; e++) {
        float qv = c0[e] + c1[e] + c2[e];
        float d = qv - acc[i][e];
        sq += d * d;
      }
    }
  }
  for (int o = 32; o > 0; o >>= 1) sq += __shfl_down(sq, o);
  __syncthreads();
  if ((tid & 63) == 0) red[tid >> 6] = sq;
  __syncthreads();
  if (tid == 0) {
    float tot = red[0] + red[1] + red[2] + red[3];
    atomicAdd(&out[qu * 5 + w], -tot * (1.0f / 220.0f));
  }
}

// ---------------------------------------------------------------------------
extern "C" void kernel_launch(void* const* d_in, const int* in_sizes, int n_in,
                              void* d_out, int out_size, void* d_ws, size_t ws_size,
                              hipStream_t stream) {
  const float* support = (const float*)d_in[0];
  const float* queries = (const float*)d_in[1];
  // d_in[2] = support_labels (sorted by construction; unused)
  const float* kw = (const float*)d_in[3];
  const float* kb = (const float*)d_in[4];
  const float* vw = (const float*)d_in[5];
  const float* vb = (const float*)d_in[6];
  const float* g  = (const float*)d_in[7];
  const float* bb = (const float*)d_in[8];
  float* out = (float*)d_out;

  float* ws = (float*)d_ws;
  size_t off = 0;
  auto alloc = [&](size_t n) { float* p = ws + off; off += (n + 63) & ~(size_t)63; return p; };
  float* PE     = alloc(12 * DIM);
  float* F      = alloc((size_t)NROWS * DIM);
  float* Ck     = alloc((size_t)NPROJ * DIM);
  float* Cv     = alloc((size_t)NPROJ * DIM);
  float* G      = alloc((size_t)2 * 1800 * 900);
  float* m_arr  = alloc(NPROJ);
  float* A_arr  = alloc(2 * NPROJ);
  float* B_arr  = alloc(2 * NPROJ);
  float* S      = alloc(75 * 1296);
  float* mu_arr = alloc(75 * NTUP);
  float* r_arr  = alloc(75 * NTUP);
  float* zg     = alloc(2 * 75 * NTUP);
  float* zb     = alloc(2 * 75 * NTUP);
  float* consts = alloc(64);
  int* tup   = (int*)alloc(660);
  int* cnt   = (int*)alloc(64);
  int* lists = (int*)alloc(2304);

  hipMemsetAsync(d_out, 0, (size_t)out_size * sizeof(float), stream);

  init_tables<<<1, 256, 0, stream>>>(g, bb, tup, cnt, lists, consts);
  pe_kernel<<<(12 * DIM + 255) / 256, 256, 0, stream>>>(PE);
  add_pe<<<(NROWS * DIM + 255) / 256, 256, 0, stream>>>(support, queries, PE, F);
  gemm_proj<<<dim3(108, 15), 256, 0, stream>>>(F, kw, vw, kb, vb, Ck, Cv);
  row_stats<<<NPROJ, 128, 0, stream>>>(Ck, g, bb, m_arr, A_arr, B_arr);
  self_gram<<<75, 256, 0, stream>>>(Ck, S);
  row_ln<<<75, 256, 0, stream>>>(S, m_arr, A_arr, B_arr, tup, mu_arr, r_arr, zg, zb);
  cross_gram<<<dim3(15, 29, 2), 256, 0, stream>>>(Ck, g, G);
  attn_kernel<<<dim3(14, 5, 100), 256, 0, stream>>>(G, Cv, mu_arr, r_arr, zg, zb,
                                                    tup, cnt, lists, consts, out);
}

// Round 3
// 2254.309 us; speedup vs baseline: 1.4678x; 1.4678x over previous
//
#include <hip/hip_runtime.h>
#include <math.h>

// ---------------------------------------------------------------------------
// MultiTemporalCrossTransformer — factorized algorithm, round 3.
//   * projections via bf16 MFMA GEMM (frame-factorized: 900x6912x1152)
//   * LN stats from per-frame means + fp32 self-Gram
//   * scores from g-weighted bf16 cross-Gram + R-precompute (3-pt gather)
//   * wave-autonomous softmax (no block barriers in score loop)
//   * tuple-marginalized PV + fused distance
// ---------------------------------------------------------------------------

#define DIM 1152
#define HDIM 576
#define NTUP 220
#define CHUNK 16

typedef __attribute__((ext_vector_type(4))) float f32x4;
typedef __attribute__((ext_vector_type(8))) short short8;

__device__ __forceinline__ ushort f2bf(float x) {
  union { float f; unsigned u; } v; v.f = x;
  unsigned r = (v.u + 0x7FFFu + ((v.u >> 16) & 1u)) >> 16;
  return (ushort)r;
}
__device__ __forceinline__ float bf2f(ushort x) {
  union { unsigned u; float f; } v; v.u = ((unsigned)x) << 16;
  return v.f;
}

// ---------------- init: tuple tables, inverse lists, g/b constants ---------
__global__ __launch_bounds__(256) void init_tables(
    const float* __restrict__ g, const float* __restrict__ bb,
    int* __restrict__ tup, uint* __restrict__ tupP, int* __restrict__ cnt,
    int* __restrict__ lists, float* __restrict__ consts)
{
  const int tid = threadIdx.x;
  if (tid < 220) {
    int t = tid, idx = 0;
    for (int a = 0; a < 10; a++)
      for (int b2 = a + 1; b2 < 11; b2++)
        for (int c = b2 + 1; c < 12; c++) {
          if (idx == t) {
            tup[t*3+0]=a; tup[t*3+1]=b2; tup[t*3+2]=c;
            tupP[t] = (uint)a | ((uint)b2 << 8) | ((uint)c << 16);
          }
          idx++;
        }
  }
  __syncthreads();
  if (tid < 36) {
    int j = tid / 12, p = tid % 12, c = 0;
    for (int t = 0; t < 220; t++)
      if (tup[t*3+j] == p) lists[tid*64 + (c++)] = t;
    cnt[tid] = c;
  }
  __shared__ float rd[6];
  if (tid < 6) rd[tid] = 0.f;
  __syncthreads();
  float s[6] = {0,0,0,0,0,0};
  for (int d = tid; d < DIM; d += 256) {
    float gv = g[d], bv = bb[d];
    int h = (d >= HDIM);
    s[h]     += gv*gv;
    s[2 + h] += gv*bv;
    s[4 + h] += bv*bv;
  }
  for (int i = 0; i < 6; i++) atomicAdd(&rd[i], s[i]);
  __syncthreads();
  if (tid < 6) consts[tid] = rd[tid];
}

// ---------------- positional encoding (float64, matches numpy) -------------
__global__ __launch_bounds__(256) void pe_kernel(float* __restrict__ PE)
{
  int idx = blockIdx.x * 256 + threadIdx.x;
  if (idx >= 12 * DIM) return;
  int p = idx / DIM, d = idx - p * DIM;
  int j = d >> 1;
  double div = exp((double)(2 * j) * (-9.210340371976184 / 1152.0));
  double ang = (double)p * div;
  double v = (d & 1) ? cos(ang) : sin(ang);
  PE[idx] = (float)(v * 0.1);
}

// ---------------- Fb = bf16(input + PE) ------------------------------------
__global__ __launch_bounds__(256) void add_pe_bf(
    const float* __restrict__ sup, const float* __restrict__ qry,
    const float* __restrict__ PE, ushort* __restrict__ Fb)
{
  int idx = blockIdx.x * 256 + threadIdx.x;
  if (idx >= 900 * DIM) return;
  int row = idx / DIM, d = idx - row * DIM;
  int p = row % 12;
  float x = (row < 300) ? sup[idx] : qry[idx - 300 * DIM];
  Fb[idx] = f2bf(x + PE[p * DIM + d]);
}

// ---------------- W transpose+convert: Wt[n][k] bf16 -----------------------
__global__ __launch_bounds__(256) void conv_w(
    const float* __restrict__ kw, const float* __restrict__ vw,
    ushort* __restrict__ Wt)
{
  __shared__ float tileS[32][33];
  const int tid = threadIdx.x;
  const int kt = blockIdx.x * 32;    // K base
  const int ng0 = blockIdx.y * 32;   // N base (0..6880)
  const int b = ng0 / DIM, d0 = ng0 - b * DIM;
  const float* src = (b < 3) ? (kw + (size_t)b * DIM * DIM)
                             : (vw + (size_t)(b - 3) * DIM * DIM);
  const int r = tid >> 3, cs = (tid & 7) * 4;
  float4 vsrc = *(const float4*)(src + (size_t)(kt + r) * DIM + d0 + cs);
  tileS[r][cs+0] = vsrc.x; tileS[r][cs+1] = vsrc.y;
  tileS[r][cs+2] = vsrc.z; tileS[r][cs+3] = vsrc.w;
  __syncthreads();
  uint u0 = (uint)f2bf(tileS[cs+0][r]) | ((uint)f2bf(tileS[cs+1][r]) << 16);
  uint u1 = (uint)f2bf(tileS[cs+2][r]) | ((uint)f2bf(tileS[cs+3][r]) << 16);
  uint2 o; o.x = u0; o.y = u1;
  *(uint2*)(Wt + (size_t)(ng0 + r) * DIM + kt + cs) = o;
}

// ---------------- projection MFMA GEMM: C[900,6912] = Fb @ Wt^T ------------
__global__ __launch_bounds__(256) void gemm_proj_mfma(
    const ushort* __restrict__ Fb, const ushort* __restrict__ Wt,
    const float* __restrict__ kb, const float* __restrict__ vb,
    float* __restrict__ Ck, float* __restrict__ Cv)
{
  __shared__ __align__(16) ushort As[128][72];
  __shared__ __align__(16) ushort Bs[128][72];
  const int tid = threadIdx.x;
  const int col0 = blockIdx.x * 128;    // 0..6784
  const int row0 = blockIdx.y * 128;    // 0..896
  f32x4 acc[4][4] = {};
  const int wv = tid >> 6, lane = tid & 63;
  const int wm = wv >> 1, wn = wv & 1;
  for (int k0 = 0; k0 < DIM; k0 += 64) {
    __syncthreads();
    for (int sidx = tid; sidx < 1024; sidx += 256) {
      int rowa = sidx >> 3, kseg = sidx & 7;
      uint4 va = {0,0,0,0};
      int gm = row0 + rowa;
      if (gm < 900) va = *(const uint4*)(Fb + (size_t)gm * DIM + k0 + kseg * 8);
      *(uint4*)&As[rowa][kseg * 8] = va;
      int gc = col0 + rowa;
      uint4 vb4 = *(const uint4*)(Wt + (size_t)gc * DIM + k0 + kseg * 8);
      *(uint4*)&Bs[rowa][kseg * 8] = vb4;
    }
    __syncthreads();
    #pragma unroll
    for (int ks = 0; ks < 64; ks += 32) {
      short8 a[4], b[4];
      #pragma unroll
      for (int i = 0; i < 4; i++) {
        a[i] = *(const short8*)&As[wm*64 + i*16 + (lane & 15)][ks + (lane >> 4) * 8];
        b[i] = *(const short8*)&Bs[wn*64 + i*16 + (lane & 15)][ks + (lane >> 4) * 8];
      }
      #pragma unroll
      for (int mi = 0; mi < 4; mi++)
        #pragma unroll
        for (int ni = 0; ni < 4; ni++)
          acc[mi][ni] = __builtin_amdgcn_mfma_f32_16x16x32_bf16(a[mi], b[ni], acc[mi][ni], 0, 0, 0);
    }
  }
  const int b = col0 / DIM, d_base = col0 - b * DIM;
  #pragma unroll
  for (int mi = 0; mi < 4; mi++)
    #pragma unroll
    for (int ni = 0; ni < 4; ni++)
      #pragma unroll
      for (int r = 0; r < 4; r++) {
        int m = row0 + wm * 64 + mi * 16 + (lane >> 4) * 4 + r;
        if (m >= 900) continue;
        int n = wn * 64 + ni * 16 + (lane & 15);
        int d = d_base + n;
        float val = acc[mi][ni][r];
        if (b < 3) Ck[((size_t)m * 3 + b)       * DIM + d] = val + kb[d] * (1.f/3.f);
        else       Cv[((size_t)m * 3 + (b - 3)) * DIM + d] = val + vb[d] * (1.f/3.f);
      }
}

// ---------------- per frame-projection row stats (fp32) --------------------
__global__ __launch_bounds__(128) void row_stats(
    const float* __restrict__ Ck, const float* __restrict__ g,
    const float* __restrict__ bb, float* __restrict__ m_o,
    float* __restrict__ A_o, float* __restrict__ B_o)
{
  const int r = blockIdx.x, tid = threadIdx.x;
  const float* x = Ck + (size_t)r * DIM;
  float sm = 0, sa0 = 0, sa1 = 0, sb0 = 0, sb1 = 0;
  for (int d = tid; d < DIM; d += 128) {
    float xv = x[d], gv = g[d], bv = bb[d];
    float xg2 = xv * gv * gv, xgb = xv * gv * bv;
    if (d < HDIM) { sa0 += xg2; sb0 += xgb; } else { sa1 += xg2; sb1 += xgb; }
    sm += xv;
  }
  for (int o = 32; o > 0; o >>= 1) {
    sm  += __shfl_down(sm, o);  sa0 += __shfl_down(sa0, o); sa1 += __shfl_down(sa1, o);
    sb0 += __shfl_down(sb0, o); sb1 += __shfl_down(sb1, o);
  }
  __shared__ float red[2][5];
  if ((tid & 63) == 0) {
    int wv = tid >> 6;
    red[wv][0]=sm; red[wv][1]=sa0; red[wv][2]=sa1; red[wv][3]=sb0; red[wv][4]=sb1;
  }
  __syncthreads();
  if (tid == 0) {
    m_o[r]         = (red[0][0] + red[1][0]) * (1.f / 1152.f);
    A_o[r]         =  red[0][1] + red[1][1];
    A_o[2700 + r]  =  red[0][2] + red[1][2];
    B_o[r]         =  red[0][3] + red[1][3];
    B_o[2700 + r]  =  red[0][4] + red[1][4];
  }
}

// ---------------- per-sequence 36x36 self-Gram (fp32, full 1152) -----------
__global__ __launch_bounds__(256) void self_gram(
    const float* __restrict__ Ck, float* __restrict__ S)
{
  const int u = blockIdx.x, tid = threadIdx.x;
  __shared__ float CS[36][129];
  float acc[2][3] = {{0,0,0},{0,0,0}};
  const int ta = tid / 12, tb = tid - (tid / 12) * 12;
  for (int k0 = 0; k0 < DIM; k0 += 128) {
    __syncthreads();
    for (int idx = tid; idx < 36 * 128; idx += 256) {
      int rr = idx >> 7, kk = idx & 127;
      CS[rr][kk] = Ck[((size_t)u * 36 + rr) * DIM + k0 + kk];
    }
    __syncthreads();
    if (ta < 18) {
      for (int kk = 0; kk < 128; kk++) {
        float va0 = CS[ta*2][kk], va1 = CS[ta*2+1][kk];
        float vb0 = CS[tb*3][kk], vb1 = CS[tb*3+1][kk], vb2 = CS[tb*3+2][kk];
        acc[0][0]+=va0*vb0; acc[0][1]+=va0*vb1; acc[0][2]+=va0*vb2;
        acc[1][0]+=va1*vb0; acc[1][1]+=va1*vb1; acc[1][2]+=va1*vb2;
      }
    }
  }
  if (ta < 18) {
    #pragma unroll
    for (int i = 0; i < 2; i++)
      #pragma unroll
      for (int j = 0; j < 3; j++)
        S[u * 1296 + (ta*2+i) * 36 + tb*3+j] = acc[i][j];
  }
}

// ---------------- per-(seq,tuple) LN stats packed: kst[2][75][220] ---------
__global__ __launch_bounds__(256) void row_ln(
    const float* __restrict__ S, const float* __restrict__ m_i,
    const float* __restrict__ A_i, const float* __restrict__ B_i,
    const int* __restrict__ tup, float4* __restrict__ kst)
{
  const int u = blockIdx.x, tid = threadIdx.x;
  __shared__ float Ss[36][36];
  __shared__ float ms[36], As[2][36], Bs[2][36];
  for (int idx = tid; idx < 1296; idx += 256) (&Ss[0][0])[idx] = S[u * 1296 + idx];
  if (tid < 36) {
    ms[tid]    = m_i[u * 36 + tid];
    As[0][tid] = A_i[u * 36 + tid];  As[1][tid] = A_i[2700 + u * 36 + tid];
    Bs[0][tid] = B_i[u * 36 + tid];  Bs[1][tid] = B_i[2700 + u * 36 + tid];
  }
  __syncthreads();
  if (tid < NTUP) {
    int a0 = tup[tid*3+0]*3+0, a1 = tup[tid*3+1]*3+1, a2 = tup[tid*3+2]*3+2;
    float mu = ms[a0] + ms[a1] + ms[a2];
    float qq = Ss[a0][a0] + Ss[a1][a1] + Ss[a2][a2]
             + 2.f * (Ss[a0][a1] + Ss[a0][a2] + Ss[a1][a2]);
    float var = qq * (1.f / 1152.f) - mu * mu;
    float rr = rsqrtf(var + 1e-5f);
    kst[((size_t)0 * 75 + u) * 220 + tid] =
        make_float4(mu, rr, As[0][a0]+As[0][a1]+As[0][a2], Bs[0][a0]+Bs[0][a1]+Bs[0][a2]);
    kst[((size_t)1 * 75 + u) * 220 + tid] =
        make_float4(mu, rr, As[1][a0]+As[1][a1]+As[1][a2], Bs[1][a0]+Bs[1][a1]+Bs[1][a2]);
  }
}

// ---------------- Ckw = bf16(Ck * g) ---------------------------------------
__global__ __launch_bounds__(256) void conv_ckw(
    const float* __restrict__ Ck, const float* __restrict__ g,
    ushort* __restrict__ Ckw)
{
  size_t i = (size_t)blockIdx.x * 256 + threadIdx.x;
  if (i >= (size_t)2700 * DIM) return;
  int d = (int)(i % DIM);
  Ckw[i] = f2bf(Ck[i] * g[d]);
}

// ---------------- cross-Gram MFMA: Gb[h][1800][900] bf16 -------------------
__global__ __launch_bounds__(256) void cross_gram_mfma(
    const ushort* __restrict__ Ckw, ushort* __restrict__ Gb)
{
  __shared__ __align__(16) ushort As[128][72];
  __shared__ __align__(16) ushort Bs[128][72];
  const int tid = threadIdx.x;
  const int col0 = blockIdx.x * 128;   // N=900
  const int row0 = blockIdx.y * 128;   // M=1800
  const int h = blockIdx.z;
  f32x4 acc[4][4] = {};
  const int wv = tid >> 6, lane = tid & 63;
  const int wm = wv >> 1, wn = wv & 1;
  for (int k0 = 0; k0 < HDIM; k0 += 64) {
    __syncthreads();
    for (int sidx = tid; sidx < 1024; sidx += 256) {
      int rowa = sidx >> 3, kseg = sidx & 7;
      uint4 va = {0,0,0,0};
      int gm = row0 + rowa;
      if (gm < 1800)
        va = *(const uint4*)(Ckw + (size_t)(900 + gm) * DIM + h * HDIM + k0 + kseg * 8);
      *(uint4*)&As[rowa][kseg * 8] = va;
      uint4 vb = {0,0,0,0};
      int gn = col0 + rowa;
      if (gn < 900)
        vb = *(const uint4*)(Ckw + (size_t)gn * DIM + h * HDIM + k0 + kseg * 8);
      *(uint4*)&Bs[rowa][kseg * 8] = vb;
    }
    __syncthreads();
    #pragma unroll
    for (int ks = 0; ks < 64; ks += 32) {
      short8 a[4], b[4];
      #pragma unroll
      for (int i = 0; i < 4; i++) {
        a[i] = *(const short8*)&As[wm*64 + i*16 + (lane & 15)][ks + (lane >> 4) * 8];
        b[i] = *(const short8*)&Bs[wn*64 + i*16 + (lane & 15)][ks + (lane >> 4) * 8];
      }
      #pragma unroll
      for (int mi = 0; mi < 4; mi++)
        #pragma unroll
        for (int ni = 0; ni < 4; ni++)
          acc[mi][ni] = __builtin_amdgcn_mfma_f32_16x16x32_bf16(a[mi], b[ni], acc[mi][ni], 0, 0, 0);
    }
  }
  #pragma unroll
  for (int mi = 0; mi < 4; mi++)
    #pragma unroll
    for (int ni = 0; ni < 4; ni++)
      #pragma unroll
      for (int r = 0; r < 4; r++) {
        int m = row0 + wm * 64 + mi * 16 + (lane >> 4) * 4 + r;
        int n = col0 + wn * 64 + ni * 16 + (lane & 15);
        if (m < 1800 && n < 900)
          Gb[((size_t)h * 1800 + m) * 900 + n] = f2bf(acc[mi][ni][r]);
      }
}

// ---------------- fused scores + softmax + marginals + PV + distance -------
struct ScoreU {
  ushort Gs[5][36][36];   // bf16 cross-gram block
  ushort sc[4][1152];     // per-wave P (bf16)
};
union SmemU {
  ScoreU s;
  ushort Vt[18][580];
};

__global__ __launch_bounds__(256) void attn_kernel(
    const ushort* __restrict__ Gb, const float* __restrict__ Cv,
    const float4* __restrict__ kst, const uint* __restrict__ tupP,
    const int* __restrict__ cnt_g, const int* __restrict__ lists_g,
    const float* __restrict__ consts, float* __restrict__ out)
{
  __shared__ __align__(16) SmemU u;
  __shared__ __align__(16) float4 kstS[5][220];
  __shared__ __align__(16) float M[CHUNK][180];
  __shared__ __align__(16) float R[4][5][36];
  __shared__ uint tupS[220];
  __shared__ unsigned char listsS[36][64];
  __shared__ unsigned char cntS[64];
  __shared__ __align__(16) float4 qst[CHUNK];
  __shared__ float red[8];

  const int tid = threadIdx.x;
  const int chunk = blockIdx.x, w = blockIdx.y;
  const int qu = blockIdx.z >> 1, h = blockIdx.z & 1;
  const int tbase = chunk * CHUNK;
  const int nt = min(CHUNK, NTUP - tbase);

  // ---- stage ----
  for (int idx = tid; idx < 3240; idx += 256) {   // Gs as uints
    int s = idx / 648, rem = idx - s * 648;
    int row = rem / 18, cu = rem - row * 18;
    size_t us = ((size_t)(h * 1800 + qu * 36 + row)) * 900 + w * 180 + s * 36;
    ((uint*)u.s.Gs)[idx] = *((const uint*)(Gb + us) + cu);
  }
  for (int idx = tid; idx < 1100; idx += 256) {
    int s = idx / 220, t2 = idx - s * 220;
    kstS[s][t2] = kst[((size_t)h * 75 + w * 5 + s) * 220 + t2];
  }
  for (int idx = tid; idx < 220; idx += 256) tupS[idx] = tupP[idx];
  for (int idx = tid; idx < 2304; idx += 256) (&listsS[0][0])[idx] = (unsigned char)lists_g[idx];
  if (tid < 36) cntS[tid] = (unsigned char)cnt_g[tid];
  if (tid < nt) qst[tid] = kst[((size_t)h * 75 + 25 + qu) * 220 + tbase + tid];
  for (int idx = tid; idx < CHUNK * 180; idx += 256) (&M[0][0])[idx] = 0.f;
  __syncthreads();

  const float Ggh = consts[h], Gbh = consts[2 + h], Bbh = consts[4 + h];
  const int wv = tid >> 6, lane = tid & 63;

  // ---- wave-autonomous scores + softmax + marginals ----
  for (int k = 0; k < 4; k++) {
    int tl = wv + 4 * k;
    if (tl >= nt) break;
    uint tq = tupS[tbase + tl];
    int a0 = (int)(tq & 255) * 3, a1 = (int)((tq >> 8) & 255) * 3 + 1,
        a2 = (int)((tq >> 16) & 255) * 3 + 2;
    #pragma unroll
    for (int pass = 0; pass < 3; pass++) {
      int ii = pass * 64 + lane;
      if (ii < 180) {
        int s = ii / 36, col = ii - s * 36;
        R[wv][s][col] = bf2f(u.s.Gs[s][a0][col]) + bf2f(u.s.Gs[s][a1][col])
                      + bf2f(u.s.Gs[s][a2][col]);
      }
    }
    asm volatile("s_waitcnt lgkmcnt(0)" ::: "memory");
    float4 q4 = qst[tl];
    const float mq = q4.x, rqv = q4.y, zgq = q4.z, zbq = q4.w;
    const float c1 = rqv * (zbq - mq * Gbh) + Bbh;
    float scl[18];
    float mx = -1e30f;
    #pragma unroll
    for (int r = 0; r < 18; r++) {
      int e = r * 64 + lane;
      float scv = -1e30f;
      if (e < 1100) {
        int s = e / 220, t2 = e - s * 220;
        uint tk = tupS[t2];
        int b0 = (int)(tk & 255) * 3, b1 = (int)((tk >> 8) & 255) * 3 + 1,
            b2 = (int)((tk >> 16) & 255) * 3 + 2;
        const float* Rs = R[wv][s];
        float GG = Rs[b0] + Rs[b1] + Rs[b2];
        float4 k4 = kstS[s][t2];
        float wqk = GG - k4.x * zgq - mq * k4.z + mq * k4.x * Ggh;
        scv = (rqv * k4.y * wqk + k4.y * (k4.w - k4.x * Gbh) + c1) * (1.f / 24.f);
      }
      scl[r] = scv;
      mx = fmaxf(mx, scv);
    }
    #pragma unroll
    for (int o = 32; o > 0; o >>= 1) mx = fmaxf(mx, __shfl_xor(mx, o));
    float sum = 0.f;
    #pragma unroll
    for (int r = 0; r < 18; r++) {
      float p = __expf(scl[r] - mx);
      sum += p;
      u.s.sc[wv][r * 64 + lane] = f2bf(p);
    }
    #pragma unroll
    for (int o = 32; o > 0; o >>= 1) sum += __shfl_xor(sum, o);
    const float inv = 1.0f / sum;
    asm volatile("s_waitcnt lgkmcnt(0)" ::: "memory");
    #pragma unroll
    for (int pass = 0; pass < 3; pass++) {
      int bin = pass * 64 + lane;
      if (bin < 180) {
        int j = bin / 60, rem = bin - j * 60, s = rem / 12, p = rem - (rem / 12) * 12;
        int c = cntS[j * 12 + p];
        const unsigned char* L = listsS[j * 12 + p];
        const ushort* scp = &u.s.sc[wv][s * 220];
        float a = 0.f;
        for (int ii2 = 0; ii2 < c; ii2++) a += bf2f(scp[L[ii2]]);
        M[tl][bin] = a * inv;
      }
    }
  }
  __syncthreads();

  // ---- PV: proto = M @ V_h (bf16 V), fused squared-distance vs q_vs ------
  float acc[2][18];
  #pragma unroll
  for (int i = 0; i < 2; i++)
    #pragma unroll
    for (int e = 0; e < 18; e++) acc[i][e] = 0.f;
  const int ty = tid >> 5, tx = tid & 31;
  const int tq0 = ty * 2, dd0 = tx * 18;
  for (int c = 0; c < 10; c++) {
    __syncthreads();
    for (int idx = tid; idx < 18 * 576; idx += 256) {
      int kk = idx / 576, dd = idx - kk * 576;
      int kg = c * 18 + kk;
      int j = kg / 60, rem = kg - j * 60, s = rem / 12, p = rem - (rem / 12) * 12;
      u.Vt[kk][dd] = f2bf(Cv[((size_t)((w * 5 + s) * 36 + p * 3 + j)) * DIM + h * HDIM + dd]);
    }
    __syncthreads();
    for (int kk = 0; kk < 18; kk++) {
      int kg = c * 18 + kk;
      float mv0 = M[tq0 + 0][kg], mv1 = M[tq0 + 1][kg];
      #pragma unroll
      for (int e = 0; e < 18; e++) {
        float vv = bf2f(u.Vt[kk][dd0 + e]);
        acc[0][e] += mv0 * vv; acc[1][e] += mv1 * vv;
      }
    }
  }

  float sq = 0.f;
  for (int i = 0; i < 2; i++) {
    int t = tbase + tq0 + i;
    if (t < NTUP) {
      uint tq = tupS[t];
      int f0 = (int)(tq & 255), f1 = (int)((tq >> 8) & 255), f2v = (int)((tq >> 16) & 255);
      const float* c0 = &Cv[((size_t)((25 + qu) * 36 + f0 * 3 + 0)) * DIM + h * HDIM + dd0];
      const float* c1p = &Cv[((size_t)((25 + qu) * 36 + f1 * 3 + 1)) * DIM + h * HDIM + dd0];
      const float* c2 = &Cv[((size_t)((25 + qu) * 36 + f2v * 3 + 2)) * DIM + h * HDIM + dd0];
      #pragma unroll
      for (int e = 0; e < 18; e++) {
        float qv = c0[e] + c1p[e] + c2[e];
        float d = qv - acc[i][e];
        sq += d * d;
      }
    }
  }
  for (int o = 32; o > 0; o >>= 1) sq += __shfl_down(sq, o);
  __syncthreads();
  if ((tid & 63) == 0) red[tid >> 6] = sq;
  __syncthreads();
  if (tid == 0) {
    float tot = red[0] + red[1] + red[2] + red[3];
    atomicAdd(&out[qu * 5 + w], -tot * (1.0f / 220.0f));
  }
}

// ---------------------------------------------------------------------------
extern "C" void kernel_launch(void* const* d_in, const int* in_sizes, int n_in,
                              void* d_out, int out_size, void* d_ws, size_t ws_size,
                              hipStream_t stream) {
  const float* support = (const float*)d_in[0];
  const float* queries = (const float*)d_in[1];
  // d_in[2] = support_labels (sorted by construction; unused)
  const float* kw = (const float*)d_in[3];
  const float* kb = (const float*)d_in[4];
  const float* vw = (const float*)d_in[5];
  const float* vb = (const float*)d_in[6];
  const float* g  = (const float*)d_in[7];
  const float* bb = (const float*)d_in[8];
  float* out = (float*)d_out;

  float* ws = (float*)d_ws;
  size_t off = 0;
  auto alloc = [&](size_t n) { float* p = ws + off; off += (n + 63) & ~(size_t)63; return p; };
  float* PE     = alloc(12 * DIM);
  // Union A: Fb (bf16 900x1152 = 518400 fl) then Ckw (bf16 2700x1152 = 1555200 fl)
  float* uA     = alloc(1555200);
  ushort* Fb    = (ushort*)uA;
  ushort* Ckw   = (ushort*)uA;
  // Union B: Wt (bf16 6912x1152 = 3981312 fl) then Gb (bf16 2x1800x900 = 1620000 fl)
  float* uB     = alloc(3981312);
  ushort* Wt    = (ushort*)uB;
  ushort* Gb    = (ushort*)uB;
  float* Ck     = alloc((size_t)2700 * DIM);
  float* Cv     = alloc((size_t)2700 * DIM);
  float* m_arr  = alloc(2700);
  float* A_arr  = alloc(2 * 2700);
  float* B_arr  = alloc(2 * 2700);
  float* S      = alloc(75 * 1296);
  float4* kst   = (float4*)alloc(2 * 75 * 220 * 4);
  float* consts = alloc(64);
  int* tup   = (int*)alloc(660);
  uint* tupP = (uint*)alloc(256);
  int* cnt   = (int*)alloc(64);
  int* lists = (int*)alloc(2304);

  hipMemsetAsync(d_out, 0, (size_t)out_size * sizeof(float), stream);

  init_tables<<<1, 256, 0, stream>>>(g, bb, tup, tupP, cnt, lists, consts);
  pe_kernel<<<(12 * DIM + 255) / 256, 256, 0, stream>>>(PE);
  add_pe_bf<<<(900 * DIM + 255) / 256, 256, 0, stream>>>(support, queries, PE, Fb);
  conv_w<<<dim3(36, 216), 256, 0, stream>>>(kw, vw, Wt);
  gemm_proj_mfma<<<dim3(54, 8), 256, 0, stream>>>(Fb, Wt, kb, vb, Ck, Cv);
  row_stats<<<2700, 128, 0, stream>>>(Ck, g, bb, m_arr, A_arr, B_arr);
  self_gram<<<75, 256, 0, stream>>>(Ck, S);
  row_ln<<<75, 256, 0, stream>>>(S, m_arr, A_arr, B_arr, tup, kst);
  conv_ckw<<<(int)(((size_t)2700 * DIM + 255) / 256), 256, 0, stream>>>(Ck, g, Ckw);
  cross_gram_mfma<<<dim3(8, 15, 2), 256, 0, stream>>>(Ckw, Gb);
  attn_kernel<<<dim3(14, 5, 100), 256, 0, stream>>>(Gb, Cv, kst, tupP, cnt, lists,
                                                    consts, out);
}